// Round 5
// baseline (637.827 us; speedup 1.0000x reference)
//
#include <hip/hip_runtime.h>
#include <hip/hip_bf16.h>
#include <math.h>

#define B_ 64
#define N_ 197
#define C_ 768
#define H_ 12
#define BN_ (B_ * N_)   // 12608
#define MPAD 12672      // workspace row padding (buffers sized to this)

typedef unsigned short ushort_t;
typedef __attribute__((ext_vector_type(8))) short short8;   // 8 x bf16 (4 VGPRs)
typedef __attribute__((ext_vector_type(4))) float f32x4;    // MFMA C/D frag

__device__ __forceinline__ float wave_reduce_sum(float v) {
#pragma unroll
  for (int off = 32; off; off >>= 1) v += __shfl_xor(v, off);
  return v;
}

__device__ __forceinline__ ushort_t f2bf(float f) {
  __hip_bfloat16 h = __float2bfloat16(f);
  ushort_t u;
  __builtin_memcpy(&u, &h, 2);
  return u;
}

__device__ __forceinline__ float gelu_fast(float u) {
  // tanh-form GELU via hw exp; max abs err ~3e-4 (<< 0.116 tolerance)
  const float z2 = 1.5957691216f * (u + 0.044715f * u * u * u);  // 2*sqrt(2/pi)*(...)
  const float e = __expf(z2);
  const float th = 1.f - 2.f / (e + 1.f);
  return 0.5f * u * (1.f + th);
}

// ---------------- weight convert + transpose: fp32 [K][N] -> bf16 [N][K] -----
__global__ __launch_bounds__(256) void wtrans_kernel(const float* __restrict__ W,
                                                     ushort_t* __restrict__ Wt,
                                                     int K, int N) {
  __shared__ ushort_t tile[32][33];
  const int bn = blockIdx.x * 32, bk = blockIdx.y * 32;
  const int tx = threadIdx.x & 31, ty = threadIdx.x >> 5;  // 32 x 8
#pragma unroll
  for (int i = ty; i < 32; i += 8)
    tile[i][tx] = f2bf(W[(size_t)(bk + i) * N + bn + tx]);
  __syncthreads();
#pragma unroll
  for (int i = ty; i < 32; i += 8)
    Wt[(size_t)(bn + i) * K + bk + tx] = tile[tx][i];
}

// ---------------- LayerNorm -> bf16 out --------------------------------------
__global__ __launch_bounds__(256) void ln_kernel(const float* __restrict__ x,
                                                 const float* __restrict__ w,
                                                 const float* __restrict__ bsh,
                                                 ushort_t* __restrict__ out) {
  const int row = blockIdx.x;
  const float* xr = x + (size_t)row * C_;
  const int tid = threadIdx.x;
  float v0 = xr[tid], v1 = xr[tid + 256], v2 = xr[tid + 512];
  float s = v0 + v1 + v2;
  float q = v0 * v0 + v1 * v1 + v2 * v2;
  s = wave_reduce_sum(s);
  q = wave_reduce_sum(q);
  __shared__ float red[8];
  const int w4 = tid >> 6, l = tid & 63;
  if (l == 0) { red[w4] = s; red[4 + w4] = q; }
  __syncthreads();
  float ts = red[0] + red[1] + red[2] + red[3];
  float tq = red[4] + red[5] + red[6] + red[7];
  float mu = ts * (1.f / C_);
  float var = tq * (1.f / C_) - mu * mu;
  float rs = rsqrtf(var + 1e-5f);
  ushort_t* orow = out + (size_t)row * C_;
  orow[tid]       = f2bf((v0 - mu) * rs * w[tid]       + bsh[tid]);
  orow[tid + 256] = f2bf((v1 - mu) * rs * w[tid + 256] + bsh[tid + 256]);
  orow[tid + 512] = f2bf((v2 - mu) * rs * w[tid + 512] + bsh[tid + 512]);
}

// ---------------- bf16 MFMA GEMM: C = A(MxK) * Bt(NxK)^T + bias --------------
// Block tile 256x128, BK=32, 4 waves each owning 128x64 (8x4 of 16x16x32 MFMA).
// 12 ds_read_b128 feed 32 MFMA per K-step (vs 8:16 before) -> MFMA-pipe-bound.
// A-stage rows clamped to M-1 (garbage C rows store-guarded).
template <int RES, int ACT, int OUT_BF16>
__global__ __launch_bounds__(256, 2) void mfma_gemm(const ushort_t* __restrict__ A,
                                                    const ushort_t* __restrict__ Bt,
                                                    const float* __restrict__ bias,
                                                    const float* __restrict__ res,
                                                    void* __restrict__ Cout,
                                                    int M, int Nc, int K) {
  __shared__ __align__(16) ushort_t As[256][32];  // [m][k], 64 B rows (16 KB)
  __shared__ __align__(16) ushort_t Bs[128][32];  // [n][k] (8 KB)
  const int tid = threadIdx.x;
  const int w = tid >> 6, l = tid & 63;
  const int bm = blockIdx.y * 256, bnn = blockIdx.x * 128;
  const int quad = l >> 4, lm = l & 15;
  const int wm = (w >> 1) * 128, wn = (w & 1) * 64;

  // Staging: A = 16 chunks of 1 KB (16 rows), B = 8 chunks. Wave w stages
  // A chunks {4w..4w+3} and B chunks {2w,2w+1}. Lane l: row = chunk*16 + l/4,
  // k (l%4)*8..+7. LDS dest = wave-uniform base + lane*16.
  const int srow = l >> 2, scol = (l & 3) << 3;
  const ushort_t* ag[4];
  ushort_t* la[4];
#pragma unroll
  for (int j = 0; j < 4; j++) {
    int row = bm + (4 * w + j) * 16 + srow;
    row = row < M ? row : M - 1;  // clamp: avoids OOB reads past padded buffers
    ag[j] = A + (size_t)row * K + scol;
    la[j] = &As[(4 * w + j) * 16][0];
  }
  const ushort_t* bg[2];
  ushort_t* lb[2];
#pragma unroll
  for (int j = 0; j < 2; j++) {
    bg[j] = Bt + (size_t)(bnn + (2 * w + j) * 16 + srow) * K + scol;
    lb[j] = &Bs[(2 * w + j) * 16][0];
  }

  f32x4 acc[8][4];
#pragma unroll
  for (int mi = 0; mi < 8; mi++)
#pragma unroll
    for (int ni = 0; ni < 4; ni++) acc[mi][ni] = (f32x4){0.f, 0.f, 0.f, 0.f};

  for (int k0 = 0; k0 < K; k0 += 32) {
#pragma unroll
    for (int j = 0; j < 4; j++)
      __builtin_amdgcn_global_load_lds(
          (const __attribute__((address_space(1))) void*)(ag[j] + k0),
          (__attribute__((address_space(3))) void*)la[j], 16, 0, 0);
#pragma unroll
    for (int j = 0; j < 2; j++)
      __builtin_amdgcn_global_load_lds(
          (const __attribute__((address_space(1))) void*)(bg[j] + k0),
          (__attribute__((address_space(3))) void*)lb[j], 16, 0, 0);
    __syncthreads();  // drains vmcnt before any wave reads the tile

    short8 af[8], bf[4];
#pragma unroll
    for (int i = 0; i < 8; i++)
      af[i] = *(const short8*)&As[wm + i * 16 + lm][quad * 8];
#pragma unroll
    for (int n = 0; n < 4; n++)
      bf[n] = *(const short8*)&Bs[wn + n * 16 + lm][quad * 8];
#pragma unroll
    for (int mi = 0; mi < 8; mi++)
#pragma unroll
      for (int ni = 0; ni < 4; ni++)
        acc[mi][ni] = __builtin_amdgcn_mfma_f32_16x16x32_bf16(
            af[mi], bf[ni], acc[mi][ni], 0, 0, 0);
    __syncthreads();
  }

  // Epilogue: C/D layout col=lane&15, row=quad*4+reg.
#pragma unroll
  for (int mi = 0; mi < 8; mi++) {
#pragma unroll
    for (int ni = 0; ni < 4; ni++) {
      const int col = bnn + wn + ni * 16 + lm;
      const float bv = bias[col];
#pragma unroll
      for (int r = 0; r < 4; r++) {
        const int row = bm + wm + mi * 16 + quad * 4 + r;
        if (row < M) {
          float v = acc[mi][ni][r] + bv;
          if constexpr (RES) v += res[(size_t)row * Nc + col];
          if constexpr (ACT) v = gelu_fast(v);
          if constexpr (OUT_BF16)
            ((ushort_t*)Cout)[(size_t)row * Nc + col] = f2bf(v);
          else
            ((float*)Cout)[(size_t)row * Nc + col] = v;
        }
      }
    }
  }
}

// ---------------- MFMA attention: one block per (b,h) ------------------------
__global__ __launch_bounds__(256, 2) void attn_mfma(const ushort_t* __restrict__ qkv,
                                                    const float* __restrict__ mask,
                                                    ushort_t* __restrict__ aout,
                                                    float* __restrict__ imp) {
  __shared__ __align__(16) ushort_t Ks[208 * 64];     // (j, g^(j&7)) swizzle
  __shared__ __align__(16) ushort_t Vt[64 * 216];     // [d][j]
  __shared__ __align__(16) ushort_t Pb[4][16 * 208];  // per-wave P strip
  const int b = blockIdx.x / H_, h = blockIdx.x % H_;
  const int tid = threadIdx.x, w = tid >> 6, l = tid & 63;
  const int quad = l >> 4, lm = l & 15;
  const ushort_t* qbase = qkv + (size_t)b * N_ * 2304 + h * 64;
  const ushort_t* kbase = qbase + 768;
  const ushort_t* vbase = qbase + 1536;

  for (int idx = tid; idx < 208 * 8; idx += 256) {
    const int j = idx >> 3, g = idx & 7;
    uint4 val = make_uint4(0u, 0u, 0u, 0u);
    if (j < N_) val = *(const uint4*)(kbase + (size_t)j * 2304 + g * 8);
    *(uint4*)&Ks[j * 64 + ((g ^ (j & 7)) << 3)] = val;
  }
  for (int idx = tid; idx < 52 * 64; idx += 256) {
    const int d = idx & 63, jg = idx >> 6, j0 = jg * 4;
    ushort_t a0 = 0, a1 = 0, a2 = 0, a3 = 0;
    if (j0 + 0 < N_) a0 = vbase[(size_t)(j0 + 0) * 2304 + d];
    if (j0 + 1 < N_) a1 = vbase[(size_t)(j0 + 1) * 2304 + d];
    if (j0 + 2 < N_) a2 = vbase[(size_t)(j0 + 2) * 2304 + d];
    if (j0 + 3 < N_) a3 = vbase[(size_t)(j0 + 3) * 2304 + d];
    uint2 pk;
    pk.x = (unsigned)a0 | ((unsigned)a1 << 16);
    pk.y = (unsigned)a2 | ((unsigned)a3 << 16);
    *(uint2*)&Vt[d * 216 + j0] = pk;
  }
  float mkv[13];
#pragma unroll
  for (int t = 0; t < 13; t++) {
    const int col = t * 16 + lm;
    mkv[t] = (col < N_) ? mask[b * N_ + col] : 0.f;
  }
  float cs[13];
#pragma unroll
  for (int t = 0; t < 13; t++) cs[t] = 0.f;
  __syncthreads();

  ushort_t* pw = &Pb[w][0];
  for (int i0 = w * 16; i0 < 208; i0 += 64) {
    f32x4 accs[13];
#pragma unroll
    for (int t = 0; t < 13; t++) accs[t] = (f32x4){0.f, 0.f, 0.f, 0.f};
#pragma unroll
    for (int kh = 0; kh < 2; kh++) {
      const int k0 = kh * 32;
      const short8 aq =
          *(const short8*)(qbase + (size_t)(i0 + lm) * 2304 + k0 + quad * 8);
      const int gb = (k0 >> 3) + quad;
#pragma unroll
      for (int t = 0; t < 13; t++) {
        const int j = t * 16 + lm;
        const short8 bk = *(const short8*)&Ks[j * 64 + ((gb ^ (j & 7)) << 3)];
        accs[t] = __builtin_amdgcn_mfma_f32_16x16x32_bf16(aq, bk, accs[t], 0, 0, 0);
      }
    }
    float inv[4];
#pragma unroll
    for (int r = 0; r < 4; r++) {
      float m = -3.4e38f;
#pragma unroll
      for (int t = 0; t < 13; t++) m = fmaxf(m, accs[t][r] * 0.125f);
      m = fmaxf(m, __shfl_xor(m, 1));
      m = fmaxf(m, __shfl_xor(m, 2));
      m = fmaxf(m, __shfl_xor(m, 4));
      m = fmaxf(m, __shfl_xor(m, 8));
      float s = 0.f;
#pragma unroll
      for (int t = 0; t < 13; t++) {
        const float e = __expf(accs[t][r] * 0.125f - m) * mkv[t];
        accs[t][r] = e;
        s += e;
      }
      s += __shfl_xor(s, 1);
      s += __shfl_xor(s, 2);
      s += __shfl_xor(s, 4);
      s += __shfl_xor(s, 8);
      inv[r] = 1.f / (s + 1e-6f);
    }
    const int ibase = i0 + quad * 4;
#pragma unroll
    for (int r = 0; r < 4; r++) {
      const bool rok = (ibase + r) < N_;
#pragma unroll
      for (int t = 0; t < 13; t++) {
        const float p = accs[t][r] * inv[r];
        accs[t][r] = p;
        if (rok) cs[t] += p;
        pw[(quad * 4 + r) * 208 + t * 16 + lm] = f2bf(p);
      }
    }
    __builtin_amdgcn_wave_barrier();
    f32x4 acco[4];
#pragma unroll
    for (int n = 0; n < 4; n++) acco[n] = (f32x4){0.f, 0.f, 0.f, 0.f};
#pragma unroll
    for (int ks = 0; ks < 6; ks++) {
      const int k0 = ks * 32;
      const short8 ap = *(const short8*)&pw[lm * 208 + k0 + quad * 8];
#pragma unroll
      for (int n = 0; n < 4; n++) {
        const short8 bv = *(const short8*)&Vt[(n * 16 + lm) * 216 + k0 + quad * 8];
        acco[n] = __builtin_amdgcn_mfma_f32_16x16x32_bf16(ap, bv, acco[n], 0, 0, 0);
      }
    }
    {
      const bool lo = (quad < 2);
      short8 apt = {};
      if (lo) apt = *(const short8*)&pw[lm * 208 + 192 + quad * 8];
#pragma unroll
      for (int n = 0; n < 4; n++) {
        short8 bvt = {};
        if (lo) bvt = *(const short8*)&Vt[(n * 16 + lm) * 216 + 192 + quad * 8];
        acco[n] = __builtin_amdgcn_mfma_f32_16x16x32_bf16(apt, bvt, acco[n], 0, 0, 0);
      }
    }
#pragma unroll
    for (int r = 0; r < 4; r++) {
      const int i = ibase + r;
      if (i < N_) {
#pragma unroll
        for (int n = 0; n < 4; n++)
          aout[(size_t)(b * N_ + i) * C_ + h * 64 + n * 16 + lm] = f2bf(acco[n][r]);
      }
    }
  }
#pragma unroll
  for (int t = 0; t < 13; t++) {
    float v = cs[t];
    v += __shfl_xor(v, 16);
    v += __shfl_xor(v, 32);
    if (l < 16) {
      const int col = t * 16 + l;
      if (col < N_)
        atomicAdd(&imp[b * N_ + col], v * (1.f / (H_ * (float)N_)));
    }
  }
}

// ---------------- mask output ------------------------------------------------
__global__ __launch_bounds__(256) void mask_kernel(const float* __restrict__ imp,
                                                   const float* __restrict__ mask,
                                                   const float* __restrict__ thr,
                                                   float* __restrict__ mask_out) {
  const int i = blockIdx.x * 256 + threadIdx.x;
  if (i >= BN_) return;
  const int n = i % N_;
  const float iv = (n == 0) ? INFINITY : imp[i];
  const float m = mask[i];
  const float nm = (iv > thr[0]) ? 1.f : 0.f;
  mask_out[i] = (m > 0.f) ? nm : m;
}

extern "C" void kernel_launch(void* const* d_in, const int* in_sizes, int n_in,
                              void* d_out, int out_size, void* d_ws, size_t ws_size,
                              hipStream_t stream) {
  const float* x      = (const float*)d_in[0];
  const float* mask   = (const float*)d_in[1];
  const float* ln1_w  = (const float*)d_in[2];
  const float* ln1_b  = (const float*)d_in[3];
  const float* qkv_w  = (const float*)d_in[4];
  const float* qkv_b  = (const float*)d_in[5];
  const float* proj_w = (const float*)d_in[6];
  const float* proj_b = (const float*)d_in[7];
  const float* ln2_w  = (const float*)d_in[8];
  const float* ln2_b  = (const float*)d_in[9];
  const float* fc1_w  = (const float*)d_in[10];
  const float* fc1_b  = (const float*)d_in[11];
  const float* fc2_w  = (const float*)d_in[12];
  const float* fc2_b  = (const float*)d_in[13];
  const float* thr    = (const float*)d_in[14];

  float* out = (float*)d_out;                // x result: BN_*C_ fp32
  float* mask_out = out + (size_t)BN_ * C_;  // then BN_ fp32

  ushort_t* buf0    = (ushort_t*)d_ws;                   // qkv out / fc1 out (aliased)
  ushort_t* hbuf    = buf0 + (size_t)MPAD * 3072;        // LN out
  ushort_t* aoutb   = hbuf + (size_t)MPAD * 768;         // attention out
  ushort_t* qkv_wt  = aoutb + (size_t)MPAD * 768;        // 2304x768
  ushort_t* proj_wt = qkv_wt + (size_t)2304 * 768;       // 768x768
  ushort_t* fc1_wt  = proj_wt + (size_t)768 * 768;       // 3072x768
  ushort_t* fc2_wt  = fc1_wt + (size_t)3072 * 768;       // 768x3072
  float*    impb    = (float*)(fc2_wt + (size_t)768 * 3072);

  hipMemsetAsync(impb, 0, BN_ * sizeof(float), stream);

  wtrans_kernel<<<dim3(2304 / 32, 768 / 32), 256, 0, stream>>>(qkv_w, qkv_wt, 768, 2304);
  wtrans_kernel<<<dim3(768 / 32, 768 / 32), 256, 0, stream>>>(proj_w, proj_wt, 768, 768);
  wtrans_kernel<<<dim3(3072 / 32, 768 / 32), 256, 0, stream>>>(fc1_w, fc1_wt, 768, 3072);
  wtrans_kernel<<<dim3(768 / 32, 3072 / 32), 256, 0, stream>>>(fc2_w, fc2_wt, 3072, 768);

  const int gy = (BN_ + 255) / 256;  // 50 M-tiles (A stage rows clamped)
  ln_kernel<<<BN_, 256, 0, stream>>>(x, ln1_w, ln1_b, hbuf);
  mfma_gemm<0, 0, 1><<<dim3(2304 / 128, gy), 256, 0, stream>>>(
      hbuf, qkv_wt, qkv_b, nullptr, buf0, BN_, 2304, 768);
  attn_mfma<<<B_ * H_, 256, 0, stream>>>(buf0, mask, aoutb, impb);
  mask_kernel<<<(BN_ + 255) / 256, 256, 0, stream>>>(impb, mask, thr, mask_out);
  mfma_gemm<1, 0, 0><<<dim3(768 / 128, gy), 256, 0, stream>>>(
      aoutb, proj_wt, proj_b, x, out, BN_, 768, 768);
  ln_kernel<<<BN_, 256, 0, stream>>>(out, ln2_w, ln2_b, hbuf);
  mfma_gemm<0, 1, 1><<<dim3(3072 / 128, gy), 256, 0, stream>>>(
      hbuf, fc1_wt, fc1_b, nullptr, buf0, BN_, 3072, 768);
  mfma_gemm<1, 0, 0><<<dim3(768 / 128, gy), 256, 0, stream>>>(
      buf0, fc2_wt, fc2_b, out, out, BN_, 768, 3072);
}

// Round 6
// 601.402 us; speedup vs baseline: 1.0606x; 1.0606x over previous
//
#include <hip/hip_runtime.h>
#include <hip/hip_bf16.h>
#include <math.h>

#define B_ 64
#define N_ 197
#define C_ 768
#define H_ 12
#define BN_ (B_ * N_)   // 12608
#define MPAD 12672      // 99 * 128 (workspace row padding)

typedef unsigned short ushort_t;
typedef __attribute__((ext_vector_type(8))) short short8;   // 8 x bf16 (4 VGPRs)
typedef __attribute__((ext_vector_type(4))) float f32x4;    // MFMA C/D frag

__device__ __forceinline__ float wave_reduce_sum(float v) {
#pragma unroll
  for (int off = 32; off; off >>= 1) v += __shfl_xor(v, off);
  return v;
}

__device__ __forceinline__ ushort_t f2bf(float f) {
  __hip_bfloat16 h = __float2bfloat16(f);
  ushort_t u;
  __builtin_memcpy(&u, &h, 2);
  return u;
}

__device__ __forceinline__ float gelu_fast(float u) {
  // tanh-form GELU via hw exp; max abs err ~3e-4 (<< 0.116 tolerance)
  const float z2 = 1.5957691216f * (u + 0.044715f * u * u * u);
  const float e = __expf(z2);
  const float th = 1.f - 2.f / (e + 1.f);
  return 0.5f * u * (1.f + th);
}

// ---------------- weight convert + transpose: fp32 [K][N] -> bf16 [N][K] -----
__global__ __launch_bounds__(256) void wtrans_kernel(const float* __restrict__ W,
                                                     ushort_t* __restrict__ Wt,
                                                     int K, int N) {
  __shared__ ushort_t tile[32][33];
  const int bn = blockIdx.x * 32, bk = blockIdx.y * 32;
  const int tx = threadIdx.x & 31, ty = threadIdx.x >> 5;  // 32 x 8
#pragma unroll
  for (int i = ty; i < 32; i += 8)
    tile[i][tx] = f2bf(W[(size_t)(bk + i) * N + bn + tx]);
  __syncthreads();
#pragma unroll
  for (int i = ty; i < 32; i += 8)
    Wt[(size_t)(bn + i) * K + bk + tx] = tile[tx][i];
}

// ---------------- LayerNorm -> bf16 out --------------------------------------
__global__ __launch_bounds__(256) void ln_kernel(const float* __restrict__ x,
                                                 const float* __restrict__ w,
                                                 const float* __restrict__ bsh,
                                                 ushort_t* __restrict__ out) {
  const int row = blockIdx.x;
  const float* xr = x + (size_t)row * C_;
  const int tid = threadIdx.x;
  float v0 = xr[tid], v1 = xr[tid + 256], v2 = xr[tid + 512];
  float s = v0 + v1 + v2;
  float q = v0 * v0 + v1 * v1 + v2 * v2;
  s = wave_reduce_sum(s);
  q = wave_reduce_sum(q);
  __shared__ float red[8];
  const int w4 = tid >> 6, l = tid & 63;
  if (l == 0) { red[w4] = s; red[4 + w4] = q; }
  __syncthreads();
  float ts = red[0] + red[1] + red[2] + red[3];
  float tq = red[4] + red[5] + red[6] + red[7];
  float mu = ts * (1.f / C_);
  float var = tq * (1.f / C_) - mu * mu;
  float rs = rsqrtf(var + 1e-5f);
  ushort_t* orow = out + (size_t)row * C_;
  orow[tid]       = f2bf((v0 - mu) * rs * w[tid]       + bsh[tid]);
  orow[tid + 256] = f2bf((v1 - mu) * rs * w[tid + 256] + bsh[tid + 256]);
  orow[tid + 512] = f2bf((v2 - mu) * rs * w[tid + 512] + bsh[tid + 512]);
}

// ---------------- bf16 MFMA GEMM: C = A(MxK) * Bt(NxK)^T + bias --------------
// 128x128 tile, BK=32, 256 threads (4 waves, 2x2 of 64x64), 16x16x32 MFMA.
// LDS k-octet XOR swizzle: (row r, k-group g) stored at slot g^((r>>1)&3).
// Staging source per lane: g = (l&3)^((l>>3)&3) (LDS dest stays base+l*16).
// Frag read slot: quad^((lm>>1)&3) -> 16 lanes cover all 8 bank-groups 2x
// (2-way = free, m136), killing the 8-way conflict of the linear layout.
template <int RES, int ACT, int OUT_BF16>
__global__ __launch_bounds__(256) void mfma_gemm(const ushort_t* __restrict__ A,
                                                 const ushort_t* __restrict__ Bt,
                                                 const float* __restrict__ bias,
                                                 const float* __restrict__ res,
                                                 void* __restrict__ Cout,
                                                 int M, int Nc, int K) {
  __shared__ __align__(16) ushort_t As[128][32];  // [m][k-swizzled]
  __shared__ __align__(16) ushort_t Bs[128][32];  // [n][k-swizzled]
  const int tid = threadIdx.x;
  const int w = tid >> 6, l = tid & 63;
  const int bm = blockIdx.y * 128, bnn = blockIdx.x * 128;
  const int quad = l >> 4, lm = l & 15;
  const int wm = (w >> 1) * 64, wn = (w & 1) * 64;

  const int c0 = w * 2, c1 = w * 2 + 1;
  const int srow = l >> 2;
  const int scol = ((l & 3) ^ ((l >> 3) & 3)) << 3;  // swizzled source k-octet
  const ushort_t* ag0 = A + (size_t)(bm + c0 * 16 + srow) * K + scol;
  const ushort_t* ag1 = A + (size_t)(bm + c1 * 16 + srow) * K + scol;
  const ushort_t* bg0 = Bt + (size_t)(bnn + c0 * 16 + srow) * K + scol;
  const ushort_t* bg1 = Bt + (size_t)(bnn + c1 * 16 + srow) * K + scol;
  ushort_t* la0 = &As[c0 * 16][0];
  ushort_t* la1 = &As[c1 * 16][0];
  ushort_t* lb0 = &Bs[c0 * 16][0];
  ushort_t* lb1 = &Bs[c1 * 16][0];

  const int fslot = (quad ^ ((lm >> 1) & 3)) << 3;  // frag read slot (bytes/2)

  f32x4 acc[4][4];
#pragma unroll
  for (int mi = 0; mi < 4; mi++)
#pragma unroll
    for (int ni = 0; ni < 4; ni++) acc[mi][ni] = (f32x4){0.f, 0.f, 0.f, 0.f};

  for (int k0 = 0; k0 < K; k0 += 32) {
    __builtin_amdgcn_global_load_lds(
        (const __attribute__((address_space(1))) void*)(ag0 + k0),
        (__attribute__((address_space(3))) void*)la0, 16, 0, 0);
    __builtin_amdgcn_global_load_lds(
        (const __attribute__((address_space(1))) void*)(ag1 + k0),
        (__attribute__((address_space(3))) void*)la1, 16, 0, 0);
    __builtin_amdgcn_global_load_lds(
        (const __attribute__((address_space(1))) void*)(bg0 + k0),
        (__attribute__((address_space(3))) void*)lb0, 16, 0, 0);
    __builtin_amdgcn_global_load_lds(
        (const __attribute__((address_space(1))) void*)(bg1 + k0),
        (__attribute__((address_space(3))) void*)lb1, 16, 0, 0);
    __syncthreads();  // drains vmcnt before any wave reads the tile

    short8 af[4], bf[4];
#pragma unroll
    for (int i = 0; i < 4; i++) {
      af[i] = *(const short8*)&As[wm + i * 16 + lm][fslot];
      bf[i] = *(const short8*)&Bs[wn + i * 16 + lm][fslot];
    }
#pragma unroll
    for (int mi = 0; mi < 4; mi++)
#pragma unroll
      for (int ni = 0; ni < 4; ni++)
        acc[mi][ni] = __builtin_amdgcn_mfma_f32_16x16x32_bf16(
            af[mi], bf[ni], acc[mi][ni], 0, 0, 0);
    __syncthreads();
  }

  // Epilogue: C/D layout col=lane&15, row=quad*4+reg.
#pragma unroll
  for (int mi = 0; mi < 4; mi++) {
#pragma unroll
    for (int ni = 0; ni < 4; ni++) {
      const int col = bnn + wn + ni * 16 + lm;
      const float bv = bias[col];
#pragma unroll
      for (int r = 0; r < 4; r++) {
        const int row = bm + wm + mi * 16 + quad * 4 + r;
        if (row < M) {
          float v = acc[mi][ni][r] + bv;
          if constexpr (RES) v += res[(size_t)row * Nc + col];
          if constexpr (ACT) v = gelu_fast(v);
          if constexpr (OUT_BF16)
            ((ushort_t*)Cout)[(size_t)row * Nc + col] = f2bf(v);
          else
            ((float*)Cout)[(size_t)row * Nc + col] = v;
        }
      }
    }
  }
}

// ---------------- MFMA attention: one block per (b,h) ------------------------
__global__ __launch_bounds__(256, 2) void attn_mfma(const ushort_t* __restrict__ qkv,
                                                    const float* __restrict__ mask,
                                                    ushort_t* __restrict__ aout,
                                                    float* __restrict__ imp) {
  __shared__ __align__(16) ushort_t Ks[208 * 64];     // (j, g^(j&7)) swizzle
  __shared__ __align__(16) ushort_t Vt[64 * 216];     // [d][j]
  __shared__ __align__(16) ushort_t Pb[4][16 * 208];  // per-wave P strip
  const int b = blockIdx.x / H_, h = blockIdx.x % H_;
  const int tid = threadIdx.x, w = tid >> 6, l = tid & 63;
  const int quad = l >> 4, lm = l & 15;
  const ushort_t* qbase = qkv + (size_t)b * N_ * 2304 + h * 64;
  const ushort_t* kbase = qbase + 768;
  const ushort_t* vbase = qbase + 1536;

  for (int idx = tid; idx < 208 * 8; idx += 256) {
    const int j = idx >> 3, g = idx & 7;
    uint4 val = make_uint4(0u, 0u, 0u, 0u);
    if (j < N_) val = *(const uint4*)(kbase + (size_t)j * 2304 + g * 8);
    *(uint4*)&Ks[j * 64 + ((g ^ (j & 7)) << 3)] = val;
  }
  for (int idx = tid; idx < 52 * 64; idx += 256) {
    const int d = idx & 63, jg = idx >> 6, j0 = jg * 4;
    ushort_t a0 = 0, a1 = 0, a2 = 0, a3 = 0;
    if (j0 + 0 < N_) a0 = vbase[(size_t)(j0 + 0) * 2304 + d];
    if (j0 + 1 < N_) a1 = vbase[(size_t)(j0 + 1) * 2304 + d];
    if (j0 + 2 < N_) a2 = vbase[(size_t)(j0 + 2) * 2304 + d];
    if (j0 + 3 < N_) a3 = vbase[(size_t)(j0 + 3) * 2304 + d];
    uint2 pk;
    pk.x = (unsigned)a0 | ((unsigned)a1 << 16);
    pk.y = (unsigned)a2 | ((unsigned)a3 << 16);
    *(uint2*)&Vt[d * 216 + j0] = pk;
  }
  float mkv[13];
#pragma unroll
  for (int t = 0; t < 13; t++) {
    const int col = t * 16 + lm;
    mkv[t] = (col < N_) ? mask[b * N_ + col] : 0.f;
  }
  float cs[13];
#pragma unroll
  for (int t = 0; t < 13; t++) cs[t] = 0.f;
  __syncthreads();

  ushort_t* pw = &Pb[w][0];
  for (int i0 = w * 16; i0 < 208; i0 += 64) {
    f32x4 accs[13];
#pragma unroll
    for (int t = 0; t < 13; t++) accs[t] = (f32x4){0.f, 0.f, 0.f, 0.f};
#pragma unroll
    for (int kh = 0; kh < 2; kh++) {
      const int k0 = kh * 32;
      const short8 aq =
          *(const short8*)(qbase + (size_t)(i0 + lm) * 2304 + k0 + quad * 8);
      const int gb = (k0 >> 3) + quad;
#pragma unroll
      for (int t = 0; t < 13; t++) {
        const int j = t * 16 + lm;
        const short8 bk = *(const short8*)&Ks[j * 64 + ((gb ^ (j & 7)) << 3)];
        accs[t] = __builtin_amdgcn_mfma_f32_16x16x32_bf16(aq, bk, accs[t], 0, 0, 0);
      }
    }
    float inv[4];
#pragma unroll
    for (int r = 0; r < 4; r++) {
      float m = -3.4e38f;
#pragma unroll
      for (int t = 0; t < 13; t++) m = fmaxf(m, accs[t][r] * 0.125f);
      m = fmaxf(m, __shfl_xor(m, 1));
      m = fmaxf(m, __shfl_xor(m, 2));
      m = fmaxf(m, __shfl_xor(m, 4));
      m = fmaxf(m, __shfl_xor(m, 8));
      float s = 0.f;
#pragma unroll
      for (int t = 0; t < 13; t++) {
        const float e = __expf(accs[t][r] * 0.125f - m) * mkv[t];
        accs[t][r] = e;
        s += e;
      }
      s += __shfl_xor(s, 1);
      s += __shfl_xor(s, 2);
      s += __shfl_xor(s, 4);
      s += __shfl_xor(s, 8);
      inv[r] = 1.f / (s + 1e-6f);
    }
    const int ibase = i0 + quad * 4;
#pragma unroll
    for (int r = 0; r < 4; r++) {
      const bool rok = (ibase + r) < N_;
#pragma unroll
      for (int t = 0; t < 13; t++) {
        const float p = accs[t][r] * inv[r];
        accs[t][r] = p;
        if (rok) cs[t] += p;
        pw[(quad * 4 + r) * 208 + t * 16 + lm] = f2bf(p);
      }
    }
    __builtin_amdgcn_wave_barrier();
    f32x4 acco[4];
#pragma unroll
    for (int n = 0; n < 4; n++) acco[n] = (f32x4){0.f, 0.f, 0.f, 0.f};
#pragma unroll
    for (int ks = 0; ks < 6; ks++) {
      const int k0 = ks * 32;
      const short8 ap = *(const short8*)&pw[lm * 208 + k0 + quad * 8];
#pragma unroll
      for (int n = 0; n < 4; n++) {
        const short8 bv = *(const short8*)&Vt[(n * 16 + lm) * 216 + k0 + quad * 8];
        acco[n] = __builtin_amdgcn_mfma_f32_16x16x32_bf16(ap, bv, acco[n], 0, 0, 0);
      }
    }
    {
      const bool lo = (quad < 2);
      short8 apt = {};
      if (lo) apt = *(const short8*)&pw[lm * 208 + 192 + quad * 8];
#pragma unroll
      for (int n = 0; n < 4; n++) {
        short8 bvt = {};
        if (lo) bvt = *(const short8*)&Vt[(n * 16 + lm) * 216 + 192 + quad * 8];
        acco[n] = __builtin_amdgcn_mfma_f32_16x16x32_bf16(apt, bvt, acco[n], 0, 0, 0);
      }
    }
#pragma unroll
    for (int r = 0; r < 4; r++) {
      const int i = ibase + r;
      if (i < N_) {
#pragma unroll
        for (int n = 0; n < 4; n++)
          aout[(size_t)(b * N_ + i) * C_ + h * 64 + n * 16 + lm] = f2bf(acco[n][r]);
      }
    }
  }
#pragma unroll
  for (int t = 0; t < 13; t++) {
    float v = cs[t];
    v += __shfl_xor(v, 16);
    v += __shfl_xor(v, 32);
    if (l < 16) {
      const int col = t * 16 + l;
      if (col < N_)
        atomicAdd(&imp[b * N_ + col], v * (1.f / (H_ * (float)N_)));
    }
  }
}

// ---------------- mask output ------------------------------------------------
__global__ __launch_bounds__(256) void mask_kernel(const float* __restrict__ imp,
                                                   const float* __restrict__ mask,
                                                   const float* __restrict__ thr,
                                                   float* __restrict__ mask_out) {
  const int i = blockIdx.x * 256 + threadIdx.x;
  if (i >= BN_) return;
  const int n = i % N_;
  const float iv = (n == 0) ? INFINITY : imp[i];
  const float m = mask[i];
  const float nm = (iv > thr[0]) ? 1.f : 0.f;
  mask_out[i] = (m > 0.f) ? nm : m;
}

extern "C" void kernel_launch(void* const* d_in, const int* in_sizes, int n_in,
                              void* d_out, int out_size, void* d_ws, size_t ws_size,
                              hipStream_t stream) {
  const float* x      = (const float*)d_in[0];
  const float* mask   = (const float*)d_in[1];
  const float* ln1_w  = (const float*)d_in[2];
  const float* ln1_b  = (const float*)d_in[3];
  const float* qkv_w  = (const float*)d_in[4];
  const float* qkv_b  = (const float*)d_in[5];
  const float* proj_w = (const float*)d_in[6];
  const float* proj_b = (const float*)d_in[7];
  const float* ln2_w  = (const float*)d_in[8];
  const float* ln2_b  = (const float*)d_in[9];
  const float* fc1_w  = (const float*)d_in[10];
  const float* fc1_b  = (const float*)d_in[11];
  const float* fc2_w  = (const float*)d_in[12];
  const float* fc2_b  = (const float*)d_in[13];
  const float* thr    = (const float*)d_in[14];

  float* out = (float*)d_out;                // x result: BN_*C_ fp32
  float* mask_out = out + (size_t)BN_ * C_;  // then BN_ fp32

  ushort_t* buf0    = (ushort_t*)d_ws;                   // qkv out / fc1 out (aliased)
  ushort_t* hbuf    = buf0 + (size_t)MPAD * 3072;        // LN out
  ushort_t* aoutb   = hbuf + (size_t)MPAD * 768;         // attention out
  ushort_t* qkv_wt  = aoutb + (size_t)MPAD * 768;        // 2304x768
  ushort_t* proj_wt = qkv_wt + (size_t)2304 * 768;       // 768x768
  ushort_t* fc1_wt  = proj_wt + (size_t)768 * 768;       // 3072x768
  ushort_t* fc2_wt  = fc1_wt + (size_t)3072 * 768;       // 768x3072
  float*    impb    = (float*)(fc2_wt + (size_t)768 * 3072);

  hipMemsetAsync(impb, 0, BN_ * sizeof(float), stream);

  wtrans_kernel<<<dim3(2304 / 32, 768 / 32), 256, 0, stream>>>(qkv_w, qkv_wt, 768, 2304);
  wtrans_kernel<<<dim3(768 / 32, 768 / 32), 256, 0, stream>>>(proj_w, proj_wt, 768, 768);
  wtrans_kernel<<<dim3(3072 / 32, 768 / 32), 256, 0, stream>>>(fc1_w, fc1_wt, 768, 3072);
  wtrans_kernel<<<dim3(768 / 32, 3072 / 32), 256, 0, stream>>>(fc2_w, fc2_wt, 3072, 768);

  const int gy = MPAD / 128;  // 99 M-tiles (workspace buffers are MPAD rows)
  ln_kernel<<<BN_, 256, 0, stream>>>(x, ln1_w, ln1_b, hbuf);
  mfma_gemm<0, 0, 1><<<dim3(2304 / 128, gy), 256, 0, stream>>>(
      hbuf, qkv_wt, qkv_b, nullptr, buf0, BN_, 2304, 768);
  attn_mfma<<<B_ * H_, 256, 0, stream>>>(buf0, mask, aoutb, impb);
  mask_kernel<<<(BN_ + 255) / 256, 256, 0, stream>>>(impb, mask, thr, mask_out);
  mfma_gemm<1, 0, 0><<<dim3(768 / 128, gy), 256, 0, stream>>>(
      aoutb, proj_wt, proj_b, x, out, BN_, 768, 768);
  ln_kernel<<<BN_, 256, 0, stream>>>(out, ln2_w, ln2_b, hbuf);
  mfma_gemm<0, 1, 1><<<dim3(3072 / 128, gy), 256, 0, stream>>>(
      hbuf, fc1_wt, fc1_b, nullptr, buf0, BN_, 3072, 768);
  mfma_gemm<1, 0, 0><<<dim3(768 / 128, gy), 256, 0, stream>>>(
      buf0, fc2_wt, fc2_b, out, out, BN_, 768, 3072);
}

// Round 7
// 571.686 us; speedup vs baseline: 1.1157x; 1.0520x over previous
//
#include <hip/hip_runtime.h>
#include <hip/hip_bf16.h>
#include <math.h>

#define B_ 64
#define N_ 197
#define C_ 768
#define H_ 12
#define BN_ (B_ * N_)   // 12608
#define MPAD 12672      // 99 * 128 (workspace row padding)
#define GRIDM 99        // M-tiles (128-row)

typedef unsigned short ushort_t;
typedef __attribute__((ext_vector_type(8))) short short8;   // 8 x bf16 (4 VGPRs)
typedef __attribute__((ext_vector_type(4))) float f32x4;    // MFMA C/D frag

__device__ __forceinline__ float wave_reduce_sum(float v) {
#pragma unroll
  for (int off = 32; off; off >>= 1) v += __shfl_xor(v, off);
  return v;
}

__device__ __forceinline__ ushort_t f2bf(float f) {
  __hip_bfloat16 h = __float2bfloat16(f);
  ushort_t u;
  __builtin_memcpy(&u, &h, 2);
  return u;
}

__device__ __forceinline__ float gelu_fast(float u) {
  // tanh-form GELU via hw exp; max abs err ~3e-4 (<< 0.116 tolerance)
  const float z2 = 1.5957691216f * (u + 0.044715f * u * u * u);
  const float e = __expf(z2);
  const float th = 1.f - 2.f / (e + 1.f);
  return 0.5f * u * (1.f + th);
}

// ---------------- weight convert + transpose: fp32 [K][N] -> bf16 [N][K] -----
__global__ __launch_bounds__(256) void wtrans_kernel(const float* __restrict__ W,
                                                     ushort_t* __restrict__ Wt,
                                                     int K, int N) {
  __shared__ ushort_t tile[32][33];
  const int bn = blockIdx.x * 32, bk = blockIdx.y * 32;
  const int tx = threadIdx.x & 31, ty = threadIdx.x >> 5;  // 32 x 8
#pragma unroll
  for (int i = ty; i < 32; i += 8)
    tile[i][tx] = f2bf(W[(size_t)(bk + i) * N + bn + tx]);
  __syncthreads();
#pragma unroll
  for (int i = ty; i < 32; i += 8)
    Wt[(size_t)(bn + i) * K + bk + tx] = tile[tx][i];
}

// ---------------- LayerNorm -> bf16 out --------------------------------------
__global__ __launch_bounds__(256) void ln_kernel(const float* __restrict__ x,
                                                 const float* __restrict__ w,
                                                 const float* __restrict__ bsh,
                                                 ushort_t* __restrict__ out) {
  const int row = blockIdx.x;
  const float* xr = x + (size_t)row * C_;
  const int tid = threadIdx.x;
  float v0 = xr[tid], v1 = xr[tid + 256], v2 = xr[tid + 512];
  float s = v0 + v1 + v2;
  float q = v0 * v0 + v1 * v1 + v2 * v2;
  s = wave_reduce_sum(s);
  q = wave_reduce_sum(q);
  __shared__ float red[8];
  const int w4 = tid >> 6, l = tid & 63;
  if (l == 0) { red[w4] = s; red[4 + w4] = q; }
  __syncthreads();
  float ts = red[0] + red[1] + red[2] + red[3];
  float tq = red[4] + red[5] + red[6] + red[7];
  float mu = ts * (1.f / C_);
  float var = tq * (1.f / C_) - mu * mu;
  float rs = rsqrtf(var + 1e-5f);
  ushort_t* orow = out + (size_t)row * C_;
  orow[tid]       = f2bf((v0 - mu) * rs * w[tid]       + bsh[tid]);
  orow[tid + 256] = f2bf((v1 - mu) * rs * w[tid + 256] + bsh[tid + 256]);
  orow[tid + 512] = f2bf((v2 - mu) * rs * w[tid + 512] + bsh[tid + 512]);
}

// ---------------- bf16 MFMA GEMM: C = A(MxK) * Bt(NxK)^T + bias --------------
// 128x128 tile, BK=32, 4 waves (2x2 of 64x64), 16x16x32 MFMA, LDS XOR swizzle
// (0 bank conflicts, verified r6). New in r7:
//  - double-buffered LDS, ONE barrier per K-iter; next tile's global_load_lds
//    issued right after the barrier so it flies during the MFMA phase.
//  - XCD-aware block swizzle: flat%8 = XCD (round-robin dispatch); each XCD
//    walks N-tiles fastest within an M-tile so the A-tile stays L2-local.
template <int RES, int ACT, int OUT_BF16>
__global__ __launch_bounds__(256) void mfma_gemm(const ushort_t* __restrict__ A,
                                                 const ushort_t* __restrict__ Bt,
                                                 const float* __restrict__ bias,
                                                 const float* __restrict__ res,
                                                 void* __restrict__ Cout,
                                                 int M, int Nc, int K, int gridN) {
  __shared__ __align__(16) ushort_t As[2][128][32];  // [buf][m][k-swizzled]
  __shared__ __align__(16) ushort_t Bs[2][128][32];  // [buf][n][k-swizzled]

  // XCD swizzle decode: flat = ((jj*gridN + n)<<3) + x, m_tile = jj*8 + x.
  const int flat = blockIdx.x;
  const int x8 = flat & 7, q8 = flat >> 3;
  const int n_t = q8 % gridN, jj = q8 / gridN;
  const int m_t = jj * 8 + x8;
  if (m_t >= GRIDM) return;  // block-uniform early exit (pad blocks)

  const int tid = threadIdx.x;
  const int w = tid >> 6, l = tid & 63;
  const int bm = m_t * 128, bnn = n_t * 128;
  const int quad = l >> 4, lm = l & 15;
  const int wm = (w >> 1) * 64, wn = (w & 1) * 64;

  const int c0 = w * 2, c1 = w * 2 + 1;
  const int srow = l >> 2;
  const int scol = ((l & 3) ^ ((l >> 3) & 3)) << 3;  // swizzled source k-octet
  const ushort_t* ag0 = A + (size_t)(bm + c0 * 16 + srow) * K + scol;
  const ushort_t* ag1 = A + (size_t)(bm + c1 * 16 + srow) * K + scol;
  const ushort_t* bg0 = Bt + (size_t)(bnn + c0 * 16 + srow) * K + scol;
  const ushort_t* bg1 = Bt + (size_t)(bnn + c1 * 16 + srow) * K + scol;
  ushort_t* la0[2] = {&As[0][c0 * 16][0], &As[1][c0 * 16][0]};
  ushort_t* la1[2] = {&As[0][c1 * 16][0], &As[1][c1 * 16][0]};
  ushort_t* lb0[2] = {&Bs[0][c0 * 16][0], &Bs[1][c0 * 16][0]};
  ushort_t* lb1[2] = {&Bs[0][c1 * 16][0], &Bs[1][c1 * 16][0]};

  auto stage = [&](int pb, int k0) {
    __builtin_amdgcn_global_load_lds(
        (const __attribute__((address_space(1))) void*)(ag0 + k0),
        (__attribute__((address_space(3))) void*)la0[pb], 16, 0, 0);
    __builtin_amdgcn_global_load_lds(
        (const __attribute__((address_space(1))) void*)(ag1 + k0),
        (__attribute__((address_space(3))) void*)la1[pb], 16, 0, 0);
    __builtin_amdgcn_global_load_lds(
        (const __attribute__((address_space(1))) void*)(bg0 + k0),
        (__attribute__((address_space(3))) void*)lb0[pb], 16, 0, 0);
    __builtin_amdgcn_global_load_lds(
        (const __attribute__((address_space(1))) void*)(bg1 + k0),
        (__attribute__((address_space(3))) void*)lb1[pb], 16, 0, 0);
  };

  const int fslot = (quad ^ ((lm >> 1) & 3)) << 3;  // frag read slot

  f32x4 acc[4][4];
#pragma unroll
  for (int mi = 0; mi < 4; mi++)
#pragma unroll
    for (int ni = 0; ni < 4; ni++) acc[mi][ni] = (f32x4){0.f, 0.f, 0.f, 0.f};

  const int NIT = K >> 5;
  stage(0, 0);  // prologue: tile 0 -> buf 0
  int p = 0;
  for (int it = 0; it < NIT; ++it) {
    __syncthreads();  // tile `it` resident in buf p (drains vmcnt+lgkm)
    if (it + 1 < NIT) stage(p ^ 1, (it + 1) << 5);  // in flight during MFMA

    short8 af[4], bf[4];
#pragma unroll
    for (int i = 0; i < 4; i++) {
      af[i] = *(const short8*)&As[p][wm + i * 16 + lm][fslot];
      bf[i] = *(const short8*)&Bs[p][wn + i * 16 + lm][fslot];
    }
#pragma unroll
    for (int mi = 0; mi < 4; mi++)
#pragma unroll
      for (int ni = 0; ni < 4; ni++)
        acc[mi][ni] = __builtin_amdgcn_mfma_f32_16x16x32_bf16(
            af[mi], bf[ni], acc[mi][ni], 0, 0, 0);
    p ^= 1;
  }

  // Epilogue: C/D layout col=lane&15, row=quad*4+reg.
#pragma unroll
  for (int mi = 0; mi < 4; mi++) {
#pragma unroll
    for (int ni = 0; ni < 4; ni++) {
      const int col = bnn + wn + ni * 16 + lm;
      const float bv = bias[col];
#pragma unroll
      for (int r = 0; r < 4; r++) {
        const int row = bm + wm + mi * 16 + quad * 4 + r;
        if (row < M) {
          float v = acc[mi][ni][r] + bv;
          if constexpr (RES) v += res[(size_t)row * Nc + col];
          if constexpr (ACT) v = gelu_fast(v);
          if constexpr (OUT_BF16)
            ((ushort_t*)Cout)[(size_t)row * Nc + col] = f2bf(v);
          else
            ((float*)Cout)[(size_t)row * Nc + col] = v;
        }
      }
    }
  }
}

// ---------------- MFMA attention: one block per (b,h) ------------------------
__global__ __launch_bounds__(256, 2) void attn_mfma(const ushort_t* __restrict__ qkv,
                                                    const float* __restrict__ mask,
                                                    ushort_t* __restrict__ aout,
                                                    float* __restrict__ imp) {
  __shared__ __align__(16) ushort_t Ks[208 * 64];     // (j, g^(j&7)) swizzle
  __shared__ __align__(16) ushort_t Vt[64 * 216];     // [d][j]
  __shared__ __align__(16) ushort_t Pb[4][16 * 208];  // per-wave P strip
  const int b = blockIdx.x / H_, h = blockIdx.x % H_;
  const int tid = threadIdx.x, w = tid >> 6, l = tid & 63;
  const int quad = l >> 4, lm = l & 15;
  const ushort_t* qbase = qkv + (size_t)b * N_ * 2304 + h * 64;
  const ushort_t* kbase = qbase + 768;
  const ushort_t* vbase = qbase + 1536;

  for (int idx = tid; idx < 208 * 8; idx += 256) {
    const int j = idx >> 3, g = idx & 7;
    uint4 val = make_uint4(0u, 0u, 0u, 0u);
    if (j < N_) val = *(const uint4*)(kbase + (size_t)j * 2304 + g * 8);
    *(uint4*)&Ks[j * 64 + ((g ^ (j & 7)) << 3)] = val;
  }
  for (int idx = tid; idx < 52 * 64; idx += 256) {
    const int d = idx & 63, jg = idx >> 6, j0 = jg * 4;
    ushort_t a0 = 0, a1 = 0, a2 = 0, a3 = 0;
    if (j0 + 0 < N_) a0 = vbase[(size_t)(j0 + 0) * 2304 + d];
    if (j0 + 1 < N_) a1 = vbase[(size_t)(j0 + 1) * 2304 + d];
    if (j0 + 2 < N_) a2 = vbase[(size_t)(j0 + 2) * 2304 + d];
    if (j0 + 3 < N_) a3 = vbase[(size_t)(j0 + 3) * 2304 + d];
    uint2 pk;
    pk.x = (unsigned)a0 | ((unsigned)a1 << 16);
    pk.y = (unsigned)a2 | ((unsigned)a3 << 16);
    *(uint2*)&Vt[d * 216 + j0] = pk;
  }
  float mkv[13];
#pragma unroll
  for (int t = 0; t < 13; t++) {
    const int col = t * 16 + lm;
    mkv[t] = (col < N_) ? mask[b * N_ + col] : 0.f;
  }
  float cs[13];
#pragma unroll
  for (int t = 0; t < 13; t++) cs[t] = 0.f;
  __syncthreads();

  ushort_t* pw = &Pb[w][0];
  for (int i0 = w * 16; i0 < 208; i0 += 64) {
    f32x4 accs[13];
#pragma unroll
    for (int t = 0; t < 13; t++) accs[t] = (f32x4){0.f, 0.f, 0.f, 0.f};
#pragma unroll
    for (int kh = 0; kh < 2; kh++) {
      const int k0 = kh * 32;
      const short8 aq =
          *(const short8*)(qbase + (size_t)(i0 + lm) * 2304 + k0 + quad * 8);
      const int gb = (k0 >> 3) + quad;
#pragma unroll
      for (int t = 0; t < 13; t++) {
        const int j = t * 16 + lm;
        const short8 bk = *(const short8*)&Ks[j * 64 + ((gb ^ (j & 7)) << 3)];
        accs[t] = __builtin_amdgcn_mfma_f32_16x16x32_bf16(aq, bk, accs[t], 0, 0, 0);
      }
    }
    float inv[4];
#pragma unroll
    for (int r = 0; r < 4; r++) {
      float m = -3.4e38f;
#pragma unroll
      for (int t = 0; t < 13; t++) m = fmaxf(m, accs[t][r] * 0.125f);
      m = fmaxf(m, __shfl_xor(m, 1));
      m = fmaxf(m, __shfl_xor(m, 2));
      m = fmaxf(m, __shfl_xor(m, 4));
      m = fmaxf(m, __shfl_xor(m, 8));
      float s = 0.f;
#pragma unroll
      for (int t = 0; t < 13; t++) {
        const float e = __expf(accs[t][r] * 0.125f - m) * mkv[t];
        accs[t][r] = e;
        s += e;
      }
      s += __shfl_xor(s, 1);
      s += __shfl_xor(s, 2);
      s += __shfl_xor(s, 4);
      s += __shfl_xor(s, 8);
      inv[r] = 1.f / (s + 1e-6f);
    }
    const int ibase = i0 + quad * 4;
#pragma unroll
    for (int r = 0; r < 4; r++) {
      const bool rok = (ibase + r) < N_;
#pragma unroll
      for (int t = 0; t < 13; t++) {
        const float p = accs[t][r] * inv[r];
        accs[t][r] = p;
        if (rok) cs[t] += p;
        pw[(quad * 4 + r) * 208 + t * 16 + lm] = f2bf(p);
      }
    }
    __builtin_amdgcn_wave_barrier();
    f32x4 acco[4];
#pragma unroll
    for (int n = 0; n < 4; n++) acco[n] = (f32x4){0.f, 0.f, 0.f, 0.f};
#pragma unroll
    for (int ks = 0; ks < 6; ks++) {
      const int k0 = ks * 32;
      const short8 ap = *(const short8*)&pw[lm * 208 + k0 + quad * 8];
#pragma unroll
      for (int n = 0; n < 4; n++) {
        const short8 bv = *(const short8*)&Vt[(n * 16 + lm) * 216 + k0 + quad * 8];
        acco[n] = __builtin_amdgcn_mfma_f32_16x16x32_bf16(ap, bv, acco[n], 0, 0, 0);
      }
    }
    {
      const bool lo = (quad < 2);
      short8 apt = {};
      if (lo) apt = *(const short8*)&pw[lm * 208 + 192 + quad * 8];
#pragma unroll
      for (int n = 0; n < 4; n++) {
        short8 bvt = {};
        if (lo) bvt = *(const short8*)&Vt[(n * 16 + lm) * 216 + 192 + quad * 8];
        acco[n] = __builtin_amdgcn_mfma_f32_16x16x32_bf16(apt, bvt, acco[n], 0, 0, 0);
      }
    }
#pragma unroll
    for (int r = 0; r < 4; r++) {
      const int i = ibase + r;
      if (i < N_) {
#pragma unroll
        for (int n = 0; n < 4; n++)
          aout[(size_t)(b * N_ + i) * C_ + h * 64 + n * 16 + lm] = f2bf(acco[n][r]);
      }
    }
  }
#pragma unroll
  for (int t = 0; t < 13; t++) {
    float v = cs[t];
    v += __shfl_xor(v, 16);
    v += __shfl_xor(v, 32);
    if (l < 16) {
      const int col = t * 16 + l;
      if (col < N_)
        atomicAdd(&imp[b * N_ + col], v * (1.f / (H_ * (float)N_)));
    }
  }
}

// ---------------- mask output ------------------------------------------------
__global__ __launch_bounds__(256) void mask_kernel(const float* __restrict__ imp,
                                                   const float* __restrict__ mask,
                                                   const float* __restrict__ thr,
                                                   float* __restrict__ mask_out) {
  const int i = blockIdx.x * 256 + threadIdx.x;
  if (i >= BN_) return;
  const int n = i % N_;
  const float iv = (n == 0) ? INFINITY : imp[i];
  const float m = mask[i];
  const float nm = (iv > thr[0]) ? 1.f : 0.f;
  mask_out[i] = (m > 0.f) ? nm : m;
}

extern "C" void kernel_launch(void* const* d_in, const int* in_sizes, int n_in,
                              void* d_out, int out_size, void* d_ws, size_t ws_size,
                              hipStream_t stream) {
  const float* x      = (const float*)d_in[0];
  const float* mask   = (const float*)d_in[1];
  const float* ln1_w  = (const float*)d_in[2];
  const float* ln1_b  = (const float*)d_in[3];
  const float* qkv_w  = (const float*)d_in[4];
  const float* qkv_b  = (const float*)d_in[5];
  const float* proj_w = (const float*)d_in[6];
  const float* proj_b = (const float*)d_in[7];
  const float* ln2_w  = (const float*)d_in[8];
  const float* ln2_b  = (const float*)d_in[9];
  const float* fc1_w  = (const float*)d_in[10];
  const float* fc1_b  = (const float*)d_in[11];
  const float* fc2_w  = (const float*)d_in[12];
  const float* fc2_b  = (const float*)d_in[13];
  const float* thr    = (const float*)d_in[14];

  float* out = (float*)d_out;                // x result: BN_*C_ fp32
  float* mask_out = out + (size_t)BN_ * C_;  // then BN_ fp32

  ushort_t* buf0    = (ushort_t*)d_ws;                   // qkv out / fc1 out (aliased)
  ushort_t* hbuf    = buf0 + (size_t)MPAD * 3072;        // LN out
  ushort_t* aoutb   = hbuf + (size_t)MPAD * 768;         // attention out
  ushort_t* qkv_wt  = aoutb + (size_t)MPAD * 768;        // 2304x768
  ushort_t* proj_wt = qkv_wt + (size_t)2304 * 768;       // 768x768
  ushort_t* fc1_wt  = proj_wt + (size_t)768 * 768;       // 3072x768
  ushort_t* fc2_wt  = fc1_wt + (size_t)3072 * 768;       // 768x3072
  float*    impb    = (float*)(fc2_wt + (size_t)768 * 3072);

  hipMemsetAsync(impb, 0, BN_ * sizeof(float), stream);

  wtrans_kernel<<<dim3(2304 / 32, 768 / 32), 256, 0, stream>>>(qkv_w, qkv_wt, 768, 2304);
  wtrans_kernel<<<dim3(768 / 32, 768 / 32), 256, 0, stream>>>(proj_w, proj_wt, 768, 768);
  wtrans_kernel<<<dim3(3072 / 32, 768 / 32), 256, 0, stream>>>(fc1_w, fc1_wt, 768, 3072);
  wtrans_kernel<<<dim3(768 / 32, 3072 / 32), 256, 0, stream>>>(fc2_w, fc2_wt, 3072, 768);

  // swizzled 1D grids: ceil(GRIDM/8)=13 m-slot groups -> grid = 104 * gridN
  const int MS = 13 * 8;  // 104
  ln_kernel<<<BN_, 256, 0, stream>>>(x, ln1_w, ln1_b, hbuf);
  mfma_gemm<0, 0, 1><<<MS * 18, 256, 0, stream>>>(
      hbuf, qkv_wt, qkv_b, nullptr, buf0, BN_, 2304, 768, 18);
  attn_mfma<<<B_ * H_, 256, 0, stream>>>(buf0, mask, aoutb, impb);
  mask_kernel<<<(BN_ + 255) / 256, 256, 0, stream>>>(impb, mask, thr, mask_out);
  mfma_gemm<1, 0, 0><<<MS * 6, 256, 0, stream>>>(
      aoutb, proj_wt, proj_b, x, out, BN_, 768, 768, 6);
  ln_kernel<<<BN_, 256, 0, stream>>>(out, ln2_w, ln2_b, hbuf);
  mfma_gemm<0, 1, 1><<<MS * 24, 256, 0, stream>>>(
      hbuf, fc1_wt, fc1_b, nullptr, buf0, BN_, 3072, 768, 24);
  mfma_gemm<1, 0, 0><<<MS * 6, 256, 0, stream>>>(
      buf0, fc2_wt, fc2_b, out, out, BN_, 768, 3072, 6);
}